// Round 1
// baseline (511.819 us; speedup 1.0000x reference)
//
#include <hip/hip_runtime.h>
#include <hip/hip_bf16.h>

// out[r, n] = relu( sum_k concat[r,k] * W[k,n] ),
// concat = [review_row | user_row[perm_u] | item_row[perm_i]]
// Trick: permute W's rows once (scatter) so gathers are contiguous rows.

#define DIMS 64
#define K3 192
#define MTILE 64
#define LDST 208  // LDS row stride in bf16 units (192 + 16 pad; 16B-aligned, even bank spread)

typedef float f32x4 __attribute__((ext_vector_type(4)));
typedef short s16x8 __attribute__((ext_vector_type(8)));
typedef __bf16 bf16x8 __attribute__((ext_vector_type(8)));

__device__ __forceinline__ short f2bf(float f) {
    union { float f; unsigned int u; } v; v.f = f;
    unsigned int u = v.u;
    u += 0x7fffu + ((u >> 16) & 1u);   // round-to-nearest-even
    return (short)(u >> 16);
}

// Prep: WT[n*192 + dk] = bf16(W[k*64+n]) with dk the permuted destination k.
__global__ void prep_WT(const float* __restrict__ W,
                        const int* __restrict__ perm_u,
                        const int* __restrict__ perm_i,
                        short* __restrict__ WT) {
    const int t = threadIdx.x;
    #pragma unroll 4
    for (int i = 0; i < 48; ++i) {
        int e = t + i * 256;          // 0..12287
        int k = e >> 6;               // 0..191
        int n = e & 63;
        float w = W[e];               // coalesced: W[k*64+n]
        int dk;
        if (k < 64)       dk = k;
        else if (k < 128) dk = 64 + perm_u[k - 64];
        else              dk = 128 + perm_i[k - 128];
        WT[n * K3 + dk] = f2bf(w);
    }
}

__device__ __forceinline__ void stage16(const float* __restrict__ src, short* dst) {
    const float4* s4 = (const float4*)src;
    float4 a = s4[0], b = s4[1], c = s4[2], d = s4[3];
    s16x8 lo, hi;
    lo[0] = f2bf(a.x); lo[1] = f2bf(a.y); lo[2] = f2bf(a.z); lo[3] = f2bf(a.w);
    lo[4] = f2bf(b.x); lo[5] = f2bf(b.y); lo[6] = f2bf(b.z); lo[7] = f2bf(b.w);
    hi[0] = f2bf(c.x); hi[1] = f2bf(c.y); hi[2] = f2bf(c.z); hi[3] = f2bf(c.w);
    hi[4] = f2bf(d.x); hi[5] = f2bf(d.y); hi[6] = f2bf(d.z); hi[7] = f2bf(d.w);
    ((s16x8*)dst)[0] = lo;
    ((s16x8*)dst)[1] = hi;
}

__global__ __launch_bounds__(256) void concat_agg_kernel(
        const float* __restrict__ review,
        const float* __restrict__ user,
        const float* __restrict__ item,
        const int* __restrict__ uadj,
        const int* __restrict__ iadj,
        const short* __restrict__ WT,    // bf16 bits, [64][192] packed
        float* __restrict__ out,
        int n_reviews) {
    __shared__ short ldsX[MTILE * LDST];  // 26624 B
    __shared__ short ldsW[DIMS * LDST];   // 26624 B

    const int t = threadIdx.x;
    const int r0 = blockIdx.x * MTILE;

    // --- stage WT (1536 chunks of 8 bf16; 6 per thread) ---
    #pragma unroll
    for (int i = 0; i < 6; ++i) {
        int c = t + i * 256;
        int n = c / 24;
        int k = (c - n * 24) * 8;
        s16x8 v = *(const s16x8*)(WT + c * 8);
        *(s16x8*)&ldsW[n * LDST + k] = v;
    }

    // --- stage X: 4 threads per row, 16 floats each per segment ---
    const int rloc = t >> 2;
    const int seg  = (t & 3) * 16;
    int row = r0 + rloc;
    if (row >= n_reviews) row = n_reviews - 1;  // clamp (grid is exact here)

    stage16(review + (size_t)row * DIMS + seg, &ldsX[rloc * LDST + seg]);
    const int u  = uadj[row];
    stage16(user + (size_t)u * DIMS + seg, &ldsX[rloc * LDST + 64 + seg]);
    const int it = iadj[row];
    stage16(item + (size_t)it * DIMS + seg, &ldsX[rloc * LDST + 128 + seg]);

    __syncthreads();

    // --- MFMA: each wave does rows [16*wv,16*wv+16) x all 64 cols ---
    const int lane = t & 63;
    const int wv   = t >> 6;          // 0..3
    const int m    = lane & 15;
    const int q    = lane >> 4;       // 0..3

    const short* xa  = &ldsX[(wv * 16 + m) * LDST + q * 8];
    const short* wb0 = &ldsW[m * LDST + q * 8];

    f32x4 acc0 = {0.f,0.f,0.f,0.f}, acc1 = {0.f,0.f,0.f,0.f};
    f32x4 acc2 = {0.f,0.f,0.f,0.f}, acc3 = {0.f,0.f,0.f,0.f};

    #pragma unroll
    for (int ks = 0; ks < 6; ++ks) {
        bf16x8 a = __builtin_bit_cast(bf16x8, *(const s16x8*)(xa + ks * 32));
        bf16x8 b0 = __builtin_bit_cast(bf16x8, *(const s16x8*)(wb0 + 0 * 16 * LDST + ks * 32));
        bf16x8 b1 = __builtin_bit_cast(bf16x8, *(const s16x8*)(wb0 + 1 * 16 * LDST + ks * 32));
        bf16x8 b2 = __builtin_bit_cast(bf16x8, *(const s16x8*)(wb0 + 2 * 16 * LDST + ks * 32));
        bf16x8 b3 = __builtin_bit_cast(bf16x8, *(const s16x8*)(wb0 + 3 * 16 * LDST + ks * 32));
        acc0 = __builtin_amdgcn_mfma_f32_16x16x32_bf16(a, b0, acc0, 0, 0, 0);
        acc1 = __builtin_amdgcn_mfma_f32_16x16x32_bf16(a, b1, acc1, 0, 0, 0);
        acc2 = __builtin_amdgcn_mfma_f32_16x16x32_bf16(a, b2, acc2, 0, 0, 0);
        acc3 = __builtin_amdgcn_mfma_f32_16x16x32_bf16(a, b3, acc3, 0, 0, 0);
    }

    // --- epilogue: C/D layout col = lane&15, row = q*4 + reg ---
    #pragma unroll
    for (int v = 0; v < 4; ++v) {
        const int rr = r0 + wv * 16 + q * 4 + v;
        if (rr < n_reviews) {
            float* orow = out + (size_t)rr * DIMS + m;
            orow[ 0] = fmaxf(acc0[v], 0.0f);
            orow[16] = fmaxf(acc1[v], 0.0f);
            orow[32] = fmaxf(acc2[v], 0.0f);
            orow[48] = fmaxf(acc3[v], 0.0f);
        }
    }
}

extern "C" void kernel_launch(void* const* d_in, const int* in_sizes, int n_in,
                              void* d_out, int out_size, void* d_ws, size_t ws_size,
                              hipStream_t stream) {
    (void)n_in; (void)out_size; (void)ws_size;
    const float* review = (const float*)d_in[0];
    const float* user   = (const float*)d_in[1];
    const float* item   = (const float*)d_in[2];
    const float* W      = (const float*)d_in[3];
    const int* uadj     = (const int*)d_in[4];
    const int* iadj     = (const int*)d_in[5];
    const int* perm_u   = (const int*)d_in[6];
    const int* perm_i   = (const int*)d_in[7];
    float* out = (float*)d_out;
    short* WT = (short*)d_ws;  // 12288 bf16 = 24 KB scratch

    const int n_reviews = in_sizes[0] / DIMS;

    prep_WT<<<1, 256, 0, stream>>>(W, perm_u, perm_i, WT);

    const int grid = (n_reviews + MTILE - 1) / MTILE;
    concat_agg_kernel<<<grid, 256, 0, stream>>>(review, user, item, uadj, iadj,
                                                WT, out, n_reviews);
}